// Round 11
// baseline (884.362 us; speedup 1.0000x reference)
//
#include <hip/hip_runtime.h>
#include <hip/hip_bf16.h>
#include <hip/hip_fp16.h>

#define N 1024
#define D 128
#define SB 32          // steps per superstep (f16 gi chunk staged in LDS)
#define NSB (N / SB)

typedef __hip_bfloat16 bf16;
typedef __attribute__((ext_vector_type(4))) float fx4;
typedef __attribute__((ext_vector_type(8))) unsigned short u16x8;

__device__ __forceinline__ float b2f(bf16 x) { return __bfloat162float(x); }
__device__ __forceinline__ unsigned short f2bf_bits(float x) {
    bf16 b = __float2bfloat16(x);
    return *reinterpret_cast<unsigned short*>(&b);
}
__device__ __forceinline__ float bfbits2f(unsigned short u) {
    return __uint_as_float(((unsigned int)u) << 16);
}
__device__ __forceinline__ float fastrcp(float x) { return __builtin_amdgcn_rcpf(x); }

__device__ __forceinline__ float fast_tanh(float x) {
    float e = __expf(2.f * x);
    return 1.f - 2.f * fastrcp(e + 1.f);
}
__device__ __forceinline__ float fast_sigmoid(float x) {
    return fastrcp(1.f + __expf(-x));
}

// guaranteed packed f16 FMA: acc.{lo,hi} += a.{lo,hi} * b.{lo,hi}
__device__ __forceinline__ void pkfma(unsigned int& acc, unsigned int a, unsigned int b) {
    asm("v_pk_fma_f16 %0, %1, %2, %0" : "+v"(acc) : "v"(a), "v"(b));
}
__device__ __forceinline__ unsigned int pack_h2(float a, float b) {
    __half2 h = __floats2half2_rn(a, b);
    return *reinterpret_cast<unsigned int*>(&h);
}
__device__ __forceinline__ float h2_sumf(unsigned int u) {
    __half2 h = *reinterpret_cast<__half2*>(&u);
    return __low2float(h) + __high2float(h);
}

// flag-dispatched element load (bf16 or fp32 raw input)
__device__ __forceinline__ float ldf(const void* p, int i, int isbf) {
    return isbf ? b2f(((const bf16*)p)[i]) : ((const float*)p)[i];
}

// async 16B global->LDS: HW scatters lane i at ldsbase + i*16
__device__ __forceinline__ void async_copy16(const void* g, void* l) {
    __builtin_amdgcn_global_load_lds((const __attribute__((address_space(1))) void*)g,
                                     (__attribute__((address_space(3))) void*)l, 16, 0, 0);
}

// ---------------- K0: dtype sniff ----------------
__global__ void sniff_kernel(const unsigned short* __restrict__ xu, int* __restrict__ flag) {
    int t = threadIdx.x;  // 64
    int cnt = 0;
#pragma unroll
    for (int k = 0; k < 8; ++k) {
        unsigned short u = xu[2 * (t * 8 + k)];
        int e = (u >> 7) & 0xFF;
        cnt += (e >= 96 && e <= 144) ? 1 : 0;
    }
    for (int off = 32; off > 0; off >>= 1) cnt += __shfl_down(cnt, off);
    if (t == 0) *flag = (cnt > 400) ? 1 : 0;
}

// ---------------- K1: fused prep — qk + wihT transpose + converts ----------------
__global__ void __launch_bounds__(256) prep_kernel(const void* __restrict__ Xr,
                                                   const void* __restrict__ Wqr,
                                                   const void* __restrict__ Wkr,
                                                   const void* __restrict__ vr,
                                                   const void* __restrict__ wihr,
                                                   const void* __restrict__ whhr,
                                                   const void* __restrict__ bihr,
                                                   const void* __restrict__ bhhr,
                                                   const int* __restrict__ flag,
                                                   float* __restrict__ q, float* __restrict__ kT,
                                                   float* __restrict__ wihT,
                                                   float* __restrict__ Xf, float* __restrict__ vf,
                                                   float* __restrict__ whhf,
                                                   float* __restrict__ bihf,
                                                   float* __restrict__ bhhf) {
    int b = blockIdx.x;
    int t = threadIdx.x;
    int isbf = *flag;
    if (b < 1024) {
        __shared__ float xrow[D];
        if (t < D) xrow[t] = ldf(Xr, b * D + t, isbf);
        __syncthreads();
        if (t < D) {
            float acc = 0.f;
#pragma unroll 8
            for (int c = 0; c < D; ++c) acc += xrow[c] * ldf(Wqr, t * D + c, isbf);
            q[b * D + t] = acc;
        } else {
            int d = t - D;
            float acc = 0.f;
#pragma unroll 8
            for (int c = 0; c < D; ++c) acc += xrow[c] * ldf(Wkr, d * D + c, isbf);
            kT[d * N + b] = acc;
        }
    } else if (b < 1408) {
        int id = (b - 1024) * 256 + t;      // 98304 total
        int c = id / 384;
        int o = id - c * 384;
        wihT[id] = ldf(wihr, o * 256 + c, isbf);
    } else if (b < 1440) {
        int base = (b - 1408) * 4096;
#pragma unroll
        for (int k = 0; k < 16; ++k) {
            int i = base + k * 256 + t;
            Xf[i] = ldf(Xr, i, isbf);
        }
    } else if (b == 1440) {
        if (t < D) vf[t] = ldf(vr, t, isbf);
        for (int o = t; o < 3 * D; o += 256) {
            bihf[o] = ldf(bihr, o, isbf);
            bhhf[o] = ldf(bhhr, o, isbf);
        }
    } else {
        int base = (b - 1441) * 2048;
#pragma unroll
        for (int k = 0; k < 8; ++k) {
            int i = base + k * 256 + t;
            whhf[i] = ldf(whhr, i, isbf);
        }
    }
}

// ---------------- K2: fused scores+softmax+att+gi per row i (gi -> f16) ----------------
__global__ void __launch_bounds__(256) attn_kernel(const float* __restrict__ q,
                                                   const float* __restrict__ kT,
                                                   const float* __restrict__ v,
                                                   const float* __restrict__ X,
                                                   const float* __restrict__ wihT,
                                                   const float* __restrict__ b_ih,
                                                   __half* __restrict__ gih) {
    int i = blockIdx.x;
    __shared__ float qs[D], vs[D], xr[D], al[D];
    __shared__ float wrow[N];
    __shared__ float red[256];
    int t = threadIdx.x;
    if (t < D) { qs[t] = q[i * D + t]; vs[t] = v[t]; xr[t] = X[i * D + t]; }
    __syncthreads();

    float sj[4];
    int cnt = 0;
    float m = -1e30f;
    for (int j = i + t; j < N; j += 256) {
        float s = 0.f;
#pragma unroll 8
        for (int d = 0; d < D; ++d) s += vs[d] * fast_tanh(qs[d] + kT[d * N + j]);
        sj[cnt++] = s;
        m = fmaxf(m, s);
    }
    red[t] = m;
    __syncthreads();
    for (int st = 128; st > 0; st >>= 1) {
        if (t < st) red[t] = fmaxf(red[t], red[t + st]);
        __syncthreads();
    }
    m = red[0];
    __syncthreads();
    float lsum = 0.f;
    {
        int it = 0;
        for (int j = i + t; j < N; j += 256, ++it) {
            float p = __expf(sj[it] - m);
            wrow[j] = p;
            lsum += p;
        }
    }
    red[t] = lsum;
    __syncthreads();
    for (int st = 128; st > 0; st >>= 1) {
        if (t < st) red[t] += red[t + st];
        __syncthreads();
    }
    float inv = fastrcp(red[0]);
    __syncthreads();

    int d = t & 127, half = t >> 7;
    float acc = 0.f;
    for (int j = i + half; j < N; j += 2) acc += wrow[j] * X[j * D + d];
    if (half) red[d] = acc;
    __syncthreads();
    if (!half) al[d] = (acc + red[d]) * inv;
    __syncthreads();

    for (int o = t; o < 3 * D; o += 256) {
        float a2 = b_ih[o];
        const float* wt = wihT + o;
#pragma unroll 8
        for (int c = 0; c < D; ++c) a2 += xr[c] * wt[c * 384];
#pragma unroll 8
        for (int c = 0; c < D; ++c) a2 += al[c] * wt[(D + c) * 384];
        gih[i * 384 + o] = __float2half(a2);
    }
}

// ---------------- K3: sequential GRU via v_pk_fma_f16, 512 threads ----------------
// Thread t: d = t>>2, k-quarter kq = t&3 (lane bits[1:0] = kq). Weight rows
// {d, d+128, d+256} x K-segment [32kq,32kq+32) as 48 packed-f16 VGPRs (no spill,
// unlike R8's 96). Per step: 4 ds_read_b128 of h (4-addr broadcast, ~free),
// 48 pk_fma in 3 round-robin chains, widen+2 quad shfl_xor per gate, f32 gates
// (4x replicated per d), f16 h ping-pong + bf16 obuf, one lgkm-only barrier.
// VALU issue/SIMD/step ~= 2 waves x (48 pk + ~42 misc) x 2cyc ~= 360 cyc vs
// R6-MFMA's 466-cyc matrix-pipe floor (16x column-replication waste).
__global__ void __launch_bounds__(512, 1) gru_kernel(const __half* __restrict__ gih,
                                                     const float* __restrict__ w_hh,
                                                     const float* __restrict__ b_hh,
                                                     void* __restrict__ out,
                                                     const int* __restrict__ dflag) {
    __shared__ __align__(16) char gi_lds[2][SB * 384 * 2];   // 2 x 24 KB (f16)
    __shared__ __align__(16) unsigned int hcur[2][D / 2];    // h ping-pong, f16 packed
    __shared__ unsigned short obuf[SB][D];                   // bf16 staging, 8 KB
    int t = threadIdx.x;
    int d = t >> 2;
    int kq = t & 3;
    int w = t >> 6;
    int l = t & 63;
    int isbf = *dflag;

    // --- weights: rows d, d+128, d+256; K segment [32kq, 32kq+32), packed f16 ---
    unsigned int wr[16], wz[16], wn[16];
    {
        const float* wb = w_hh + 32 * kq;
#pragma unroll
        for (int j = 0; j < 16; ++j) {
            wr[j] = pack_h2(wb[d * D + 2 * j], wb[d * D + 2 * j + 1]);
            wz[j] = pack_h2(wb[(d + D) * D + 2 * j], wb[(d + D) * D + 2 * j + 1]);
            wn[j] = pack_h2(wb[(d + 2 * D) * D + 2 * j], wb[(d + 2 * D) * D + 2 * j + 1]);
        }
    }
    float br = b_hh[d], bz = b_hh[D + d], bn = b_hh[2 * D + d];
    float h = 0.f;

    int fr = t >> 4;            // obuf flush: row fr, 8 cols at fc
    int fc = (t & 15) * 8;

    // prefetch superstep 0 (24 KB = 24 x 1024B segments, 3 per wave)
    {
#pragma unroll
        for (int c = 0; c < 3; ++c) {
            int seg = w * 3 + c;
            async_copy16((const char*)gih + seg * 1024 + l * 16, &gi_lds[0][0] + seg * 1024);
        }
    }

    for (int sb = 0; sb < NSB; ++sb) {
        int cb = sb & 1;
        if (sb == 0) {
            if (t < 64) hcur[0][t] = 0;
        } else {
            // flush previous superstep's obuf
            u16x8 h0 = *(const u16x8*)&obuf[fr][fc];
            int orow = (sb - 1) * SB + fr;
            if (isbf) {
                *(u16x8*)((unsigned short*)out + orow * D + fc) = h0;
            } else {
                float* op = (float*)out + orow * D + fc;
                fx4 f0, f1;
#pragma unroll
                for (int j = 0; j < 4; ++j) { f0[j] = bfbits2f(h0[j]); f1[j] = bfbits2f(h0[4 + j]); }
                *(fx4*)op = f0; *(fx4*)(op + 4) = f1;
            }
        }
        // drain prefetch (issued one superstep ago) + obuf reads before rewrite
        asm volatile("s_waitcnt vmcnt(0) lgkmcnt(0)\ns_barrier" ::: "memory");

        if (sb + 1 < NSB) {
            const char* src = (const char*)gih + (size_t)(sb + 1) * SB * 384 * 2;
#pragma unroll
            for (int c = 0; c < 3; ++c) {
                int seg = w * 3 + c;
                async_copy16(src + seg * 1024 + l * 16, &gi_lds[cb ^ 1][0] + seg * 1024);
            }
        }

        const __half* gp = (const __half*)&gi_lds[cb][0] + d;   // step stride 384 halfs

        for (int s = 0; s < SB; ++s) {
            int pp = s & 1;
            // h segment: 32 f16 = 64B as 4 b128 reads (4-address broadcast)
            union { fx4 v4[4]; unsigned int u[16]; } hu;
            {
                const fx4* hp = (const fx4*)((const char*)&hcur[pp][0] + kq * 64);
#pragma unroll
                for (int j = 0; j < 4; ++j) hu.v4[j] = hp[j];
            }
            float gr = __half2float(gp[0]);
            float gz = __half2float(gp[D]);
            float gn = __half2float(gp[2 * D]);

            unsigned int ar = 0, az = 0, an = 0;
#pragma unroll
            for (int j = 0; j < 16; ++j) {
                pkfma(ar, wr[j], hu.u[j]);
                pkfma(az, wz[j], hu.u[j]);
                pkfma(an, wn[j], hu.u[j]);
            }
            float sr = h2_sumf(ar);
            float sz = h2_sumf(az);
            float sn = h2_sumf(an);
            // butterfly over the 4 kq lanes (quad DPP)
            sr += __shfl_xor(sr, 1); sr += __shfl_xor(sr, 2);
            sz += __shfl_xor(sz, 1); sz += __shfl_xor(sz, 2);
            sn += __shfl_xor(sn, 1); sn += __shfl_xor(sn, 2);

            float rr = fast_sigmoid(gr + sr + br);
            float zz = fast_sigmoid(gz + sz + bz);
            float nst = fast_tanh(gn + rr * (sn + bn));
            h = (1.f - zz) * nst + zz * h;

            if (kq == 0) {
                __half hh = __float2half(h);
                ((unsigned short*)&hcur[pp ^ 1][0])[d] = *reinterpret_cast<unsigned short*>(&hh);
                obuf[s][d] = f2bf_bits(h);
            }
            gp += 384;
            asm volatile("s_waitcnt lgkmcnt(0)\ns_barrier" ::: "memory");
        }
    }
    // final flush
    {
        u16x8 h0 = *(const u16x8*)&obuf[fr][fc];
        int orow = (NSB - 1) * SB + fr;
        if (isbf) {
            *(u16x8*)((unsigned short*)out + orow * D + fc) = h0;
        } else {
            float* op = (float*)out + orow * D + fc;
            fx4 f0, f1;
#pragma unroll
            for (int j = 0; j < 4; ++j) { f0[j] = bfbits2f(h0[j]); f1[j] = bfbits2f(h0[4 + j]); }
            *(fx4*)op = f0; *(fx4*)(op + 4) = f1;
        }
    }
}

extern "C" void kernel_launch(void* const* d_in, const int* in_sizes, int n_in,
                              void* d_out, int out_size, void* d_ws, size_t ws_size,
                              hipStream_t stream) {
    (void)in_sizes; (void)n_in; (void)out_size; (void)ws_size;

    float* w0 = (float*)d_ws;
    int*   dflag = (int*)w0;                  // 16 ints
    float* Xf   = w0 + 16;
    float* vf   = Xf   + N * D;
    float* whhf = vf   + D;
    float* bhhf = whhf + 3 * D * D;
    float* bihf = bhhf + 3 * D;
    float* q    = bihf + 3 * D;
    float* kT   = q    + N * D;
    float* wihT = kT   + N * D;
    __half* gih = (__half*)(wihT + 3 * D * 2 * D);   // N x 3D f16

    sniff_kernel<<<1, 64, 0, stream>>>((const unsigned short*)d_in[0], dflag);

    prep_kernel<<<1465, 256, 0, stream>>>(d_in[0], d_in[1], d_in[2], d_in[3],
                                          d_in[4], d_in[5], d_in[6], d_in[7],
                                          dflag, q, kT, wihT, Xf, vf, whhf, bihf, bhhf);

    attn_kernel<<<N, 256, 0, stream>>>(q, kT, vf, Xf, wihT, bihf, gih);

    gru_kernel<<<1, 512, 0, stream>>>(gih, whhf, bhhf, d_out, dflag);
}